// Round 5
// baseline (175.765 us; speedup 1.0000x reference)
//
#include <hip/hip_runtime.h>
#include <hip/hip_bf16.h>

typedef __attribute__((ext_vector_type(4))) float f32x4;
typedef __attribute__((ext_vector_type(8))) short bf16x8;

#define MFMA16(A, B, C) __builtin_amdgcn_mfma_f32_16x16x32_bf16(A, B, C, 0, 0, 0)

// 2*log2(e): tanh(x) = 1 - 2/(1 + 2^(C2*x))
#define C2 2.8853900817779268f
// C2 / sqrt(128), folded into Wq/bq so MFMA output is already exp2-scaled
#define QS (2.8853900817779268f / 11.313708498984761f)

__device__ __forceinline__ unsigned cvtpk_bf16(float lo, float hi) {
    unsigned r;
    asm("v_cvt_pk_bf16_f32 %0, %1, %2" : "=v"(r) : "v"(lo), "v"(hi));
    return r;
}

__device__ __forceinline__ bf16x8 pack8(float4 a, float4 b) {
    union { unsigned u[4]; bf16x8 v; } u;
    u.u[0] = cvtpk_bf16(a.x, a.y);
    u.u[1] = cvtpk_bf16(a.z, a.w);
    u.u[2] = cvtpk_bf16(b.x, b.y);
    u.u[3] = cvtpk_bf16(b.z, b.w);
    return u.v;
}

// ---------------------------------------------------------------------------
// Kernel 1: transpose + convert weights to bf16, fold scales, stash biases.
// ---------------------------------------------------------------------------
__global__ void prep_weights(const float* __restrict__ Wq, const float* __restrict__ bq,
                             const float* __restrict__ Wk, const float* __restrict__ bk,
                             const float* __restrict__ Wv, const float* __restrict__ bv,
                             __hip_bfloat16* __restrict__ Wqt, __hip_bfloat16* __restrict__ Wkt,
                             __hip_bfloat16* __restrict__ Wvt, float* __restrict__ bias) {
    int i = blockIdx.x * 256 + threadIdx.x;  // 64 blocks * 256 = 16384 exactly
    int k = i >> 7, o = i & 127;
    Wqt[o * 128 + k] = __float2bfloat16(Wq[i] * QS);
    Wkt[o * 128 + k] = __float2bfloat16(Wk[i]);
    Wvt[o * 128 + k] = __float2bfloat16(Wv[i] * 0.25f);  // head-mean folded into V
    if (i < 128) {
        bias[i]       = bq[i] * QS;
        bias[128 + i] = bk[i];
        bias[256 + i] = bv[i] * 0.25f;
    }
}

// ---------------------------------------------------------------------------
// Kernel 2: Q/K/V projections via 16x16x32 bf16 MFMA.
//   Qo, Ko: row-major [B*N][128] bf16 (Q pre-scaled by C2/sqrt(128))
//   Vt:     transposed [B][128][N] bf16 (pre-scaled by 0.25)
// ---------------------------------------------------------------------------
__global__ __launch_bounds__(256) void proj_qkv(
        const float* __restrict__ x, const float* __restrict__ cond,
        const __hip_bfloat16* __restrict__ Wqt, const __hip_bfloat16* __restrict__ Wkt,
        const __hip_bfloat16* __restrict__ Wvt, const float* __restrict__ bias,
        __hip_bfloat16* __restrict__ Qo, __hip_bfloat16* __restrict__ Ko,
        __hip_bfloat16* __restrict__ Vt) {
    const int lane = threadIdx.x & 63, wv = threadIdx.x >> 6;
    const int l15 = lane & 15, g = lane >> 4;
    const int row0 = blockIdx.x * 64 + wv * 16;   // 256 blocks x 64 rows

    f32x4 qa[8], ka[8], va[8];
#pragma unroll
    for (int ot = 0; ot < 8; ++ot) {
        float b0 = bias[16 * ot + l15];
        float b1 = bias[128 + 16 * ot + l15];
        float b2 = bias[256 + 16 * ot + l15];
        qa[ot] = (f32x4){b0, b0, b0, b0};
        ka[ot] = (f32x4){b1, b1, b1, b1};
        va[ot] = (f32x4){b2, b2, b2, b2};
    }

    const float* xp = x    + (size_t)(row0 + l15) * 128 + 8 * g;
    const float* cp = cond + (size_t)(row0 + l15) * 128 + 8 * g;
#pragma unroll
    for (int kk = 0; kk < 4; ++kk) {
        float4 x0 = *(const float4*)(xp + 32 * kk);
        float4 x1 = *(const float4*)(xp + 32 * kk + 4);
        float4 c0 = *(const float4*)(cp + 32 * kk);
        float4 c1 = *(const float4*)(cp + 32 * kk + 4);
        bf16x8 xa = pack8(x0, x1);
        bf16x8 ca = pack8(c0, c1);
#pragma unroll
        for (int ot = 0; ot < 8; ++ot) {
            const int wo = (16 * ot + l15) * 128 + 32 * kk + 8 * g;
            qa[ot] = MFMA16(xa, *(const bf16x8*)(Wqt + wo), qa[ot]);
            ka[ot] = MFMA16(ca, *(const bf16x8*)(Wkt + wo), ka[ot]);
            va[ot] = MFMA16(ca, *(const bf16x8*)(Wvt + wo), va[ot]);
        }
    }

    // Q, K row-major stores (C/D layout: row = 4g+r, col = 16ot+l15)
#pragma unroll
    for (int ot = 0; ot < 8; ++ot)
#pragma unroll
        for (int r = 0; r < 4; ++r) {
            size_t idx = (size_t)(row0 + 4 * g + r) * 128 + 16 * ot + l15;
            Qo[idx] = __float2bfloat16(qa[ot][r]);
            Ko[idx] = __float2bfloat16(ka[ot][r]);
        }
    // V transposed store: lane holds 4 consecutive n for fixed d -> dwordx2
    const int bb = row0 >> 11, nn = (row0 & 2047) + 4 * g;
#pragma unroll
    for (int ot = 0; ot < 8; ++ot) {
        uint2 pr;
        pr.x = cvtpk_bf16(va[ot][0], va[ot][1]);
        pr.y = cvtpk_bf16(va[ot][2], va[ot][3]);
        *(uint2*)((unsigned short*)Vt + ((size_t)bb * 128 + 16 * ot + l15) * 2048 + nn) = pr;
    }
}

// ---------------------------------------------------------------------------
// Kernel 3: fused tanh-attention main loop.
// R5: m-dimension split across 4 blocks (grid 4096) to raise resident waves
// from 16/CU to ~32/CU (R4 post-mortem: latency-bound, TLP-starved at 28.6%
// occupancy). Block = 16 q-rows x 512-m range; wave owns 128 m (2 chunks).
// Partial outputs combined with HW f32 atomics into zeroed d_out.
// Body kept at ~60 VGPR (mask prefetch removed -- it was neutral) so HW can
// run 8 waves/SIMD.
// ---------------------------------------------------------------------------
__global__ __launch_bounds__(256) void attn_main(
        const __hip_bfloat16* __restrict__ Q, const __hip_bfloat16* __restrict__ K,
        const __hip_bfloat16* __restrict__ Vt, const float* __restrict__ mask,
        float* __restrict__ out) {
    // union: per-wave bf16 transpose tiles [16][72] (9216 B) / epilogue Red
    // regions 2 x [16][132] f32 (16896 B)
    __shared__ __align__(16) char LDSB[16896];

    const int lane = threadIdx.x & 63, w = threadIdx.x >> 6;
    const int l15 = lane & 15, g = lane >> 4;
    // blockIdx = (b*4 + ms)*128 + qt : consecutive blocks share (b, m-range)
    const int qt = blockIdx.x & 127;
    const int ms = (blockIdx.x >> 7) & 3;
    const int b  = blockIdx.x >> 9;
    const int n0 = qt * 16;
    const int mbase = ms * 512 + w * 128;   // this wave's 2-chunk m-range

    unsigned* Swu = (unsigned*)LDSB + w * (16 * 36);  // wave-private, stride 36 u32
    float* Red = (float*)LDSB;

    const __hip_bfloat16* Qb = Q + ((size_t)b * 2048 + n0) * 128;
    const __hip_bfloat16* Kb = K + (size_t)b * 2048 * 128;
    const unsigned short* Vb = (const unsigned short*)Vt + (size_t)b * 128 * 2048;
    const float* mrowq = mask + ((size_t)b * 2048 + n0 + l15) * 2048;  // per-lane q-row

    bf16x8 qf[4];
#pragma unroll
    for (int h = 0; h < 4; ++h)
        qf[h] = *(const bf16x8*)(Qb + l15 * 128 + 32 * h + 8 * g);

    f32x4 oacc[8];
#pragma unroll
    for (int dt = 0; dt < 8; ++dt) oacc[dt] = (f32x4){0.f, 0.f, 0.f, 0.f};
    const f32x4 zero = (f32x4){0.f, 0.f, 0.f, 0.f};

#pragma unroll
    for (int c = 0; c < 2; ++c) {
        const int m0 = mbase + c * 64;
#pragma unroll
        for (int st = 0; st < 4; ++st) {
            const int m = m0 + st * 16;
            const __hip_bfloat16* kp = Kb + (size_t)(m + l15) * 128 + 8 * g;
            // swapped operands: D[row=4g+r -> m_local][col=l15 -> q]
            f32x4 s0 = MFMA16(*(const bf16x8*)(kp),      qf[0], zero);
            f32x4 s1 = MFMA16(*(const bf16x8*)(kp + 32), qf[1], zero);
            f32x4 s2 = MFMA16(*(const bf16x8*)(kp + 64), qf[2], zero);
            f32x4 s3 = MFMA16(*(const bf16x8*)(kp + 96), qf[3], zero);
            // coalesced mask: lane reads 4 consecutive m at its q-row
            f32x4 mk = *(const f32x4*)(mrowq + m + 4 * g);
            float acd[4];
#pragma unroll
            for (int r = 0; r < 4; ++r) {
                float m2 = mk[r] * C2;
                float e0 = __builtin_amdgcn_exp2f(m2 + s0[r]);
                float e1 = __builtin_amdgcn_exp2f(m2 + s1[r]);
                float e2 = __builtin_amdgcn_exp2f(m2 + s2[r]);
                float e3 = __builtin_amdgcn_exp2f(m2 + s3[r]);
                float rs = __builtin_amdgcn_rcpf(1.f + e0) + __builtin_amdgcn_rcpf(1.f + e1)
                         + __builtin_amdgcn_rcpf(1.f + e2) + __builtin_amdgcn_rcpf(1.f + e3);
                acd[r] = 4.f - 2.f * rs;   // sum_h tanh(...)
            }
            // packed-bf16 transpose write: row q=l15, cols m_local=16st+4g+0..3
            uint2 pk;
            pk.x = cvtpk_bf16(acd[0], acd[1]);
            pk.y = cvtpk_bf16(acd[2], acd[3]);
            *(uint2*)(Swu + l15 * 36 + st * 8 + 2 * g) = pk;
        }
        // PV: A-frag = row l15, m-slice ks*32+8g..+7 (contiguous bf16 -> b128)
#pragma unroll
        for (int ks = 0; ks < 2; ++ks) {
            bf16x8 af = *(const bf16x8*)(Swu + l15 * 36 + ks * 16 + 4 * g);
#pragma unroll
            for (int dt = 0; dt < 8; ++dt) {
                const bf16x8 vf = *(const bf16x8*)(
                    Vb + (size_t)(16 * dt + l15) * 2048 + m0 + 32 * ks + 8 * g);
                oacc[dt] = MFMA16(af, vf, oacc[dt]);
            }
        }
    }

    // epilogue: reduce 4 waves' partials in LDS, then one wave atomically
    // adds the block's 16x128 tile into out (4 blocks contribute per tile).
    __syncthreads();
    if (w >= 2)
#pragma unroll
        for (int dt = 0; dt < 8; ++dt)
#pragma unroll
            for (int r = 0; r < 4; ++r)
                Red[(w - 2) * 2112 + (4 * g + r) * 132 + 16 * dt + l15] = oacc[dt][r];
    __syncthreads();
    if (w < 2)
#pragma unroll
        for (int dt = 0; dt < 8; ++dt)
#pragma unroll
            for (int r = 0; r < 4; ++r)
                oacc[dt][r] += Red[w * 2112 + (4 * g + r) * 132 + 16 * dt + l15];
    __syncthreads();
    if (w == 1)
#pragma unroll
        for (int dt = 0; dt < 8; ++dt)
#pragma unroll
            for (int r = 0; r < 4; ++r)
                Red[(4 * g + r) * 132 + 16 * dt + l15] = oacc[dt][r];
    __syncthreads();
    if (w == 0) {
        float* ob = out + ((size_t)b * 2048 + n0) * 128;
#pragma unroll
        for (int dt = 0; dt < 8; ++dt)
#pragma unroll
            for (int r = 0; r < 4; ++r)
                unsafeAtomicAdd(&ob[(size_t)(4 * g + r) * 128 + 16 * dt + l15],
                                oacc[dt][r] + Red[(4 * g + r) * 132 + 16 * dt + l15]);
    }
}

// ---------------------------------------------------------------------------
extern "C" void kernel_launch(void* const* d_in, const int* in_sizes, int n_in,
                              void* d_out, int out_size, void* d_ws, size_t ws_size,
                              hipStream_t stream) {
    const float* x    = (const float*)d_in[0];
    const float* cond = (const float*)d_in[1];
    // d_in[2] = flags (unused by reference)
    const float* mask = (const float*)d_in[3];
    const float* Wq = (const float*)d_in[4];
    const float* bq = (const float*)d_in[5];
    const float* Wk = (const float*)d_in[6];
    const float* bk = (const float*)d_in[7];
    const float* Wv = (const float*)d_in[8];
    const float* bv = (const float*)d_in[9];
    float* out = (float*)d_out;

    char* ws = (char*)d_ws;
    __hip_bfloat16* Qo  = (__hip_bfloat16*)(ws);                       // 4 MB
    __hip_bfloat16* Ko  = (__hip_bfloat16*)(ws + (4  << 20));          // 4 MB
    __hip_bfloat16* Vt  = (__hip_bfloat16*)(ws + (8  << 20));          // 4 MB
    __hip_bfloat16* Wqt = (__hip_bfloat16*)(ws + (12 << 20));          // 32 KB
    __hip_bfloat16* Wkt = (__hip_bfloat16*)(ws + (12 << 20) + 32768);
    __hip_bfloat16* Wvt = (__hip_bfloat16*)(ws + (12 << 20) + 65536);
    float*          bias = (float*)(ws + (12 << 20) + 98304);          // 1.5 KB

    // out accumulates atomic partials from 4 m-split blocks -> zero it first
    hipMemsetAsync(d_out, 0, (size_t)out_size * sizeof(float), stream);

    prep_weights<<<64, 256, 0, stream>>>(Wq, bq, Wk, bk, Wv, bv, Wqt, Wkt, Wvt, bias);
    proj_qkv<<<256, 256, 0, stream>>>(x, cond, Wqt, Wkt, Wvt, bias, Qo, Ko, Vt);
    attn_main<<<4096, 256, 0, stream>>>(Qo, Ko, Vt, mask, out);
}

// Round 6
// 88.020 us; speedup vs baseline: 1.9969x; 1.9969x over previous
//
#include <hip/hip_runtime.h>
#include <hip/hip_bf16.h>

typedef __attribute__((ext_vector_type(4))) float f32x4;
typedef __attribute__((ext_vector_type(8))) short bf16x8;

#define MFMA16(A, B, C) __builtin_amdgcn_mfma_f32_16x16x32_bf16(A, B, C, 0, 0, 0)

// 2*log2(e): tanh(x) = 1 - 2/(1 + 2^(C2*x))
#define C2 2.8853900817779268f
// C2 / sqrt(128), folded into Wq/bq so MFMA output is already exp2-scaled
#define QS (2.8853900817779268f / 11.313708498984761f)

__device__ __forceinline__ unsigned cvtpk_bf16(float lo, float hi) {
    unsigned r;
    asm("v_cvt_pk_bf16_f32 %0, %1, %2" : "=v"(r) : "v"(lo), "v"(hi));
    return r;
}

__device__ __forceinline__ bf16x8 pack8(float4 a, float4 b) {
    union { unsigned u[4]; bf16x8 v; } u;
    u.u[0] = cvtpk_bf16(a.x, a.y);
    u.u[1] = cvtpk_bf16(a.z, a.w);
    u.u[2] = cvtpk_bf16(b.x, b.y);
    u.u[3] = cvtpk_bf16(b.z, b.w);
    return u.v;
}

// async global->LDS, 16B per lane; LDS dest = wave-uniform base + lane*16
__device__ __forceinline__ void gload_lds16(const void* g, void* l) {
    __builtin_amdgcn_global_load_lds(
        (const __attribute__((address_space(1))) unsigned int*)g,
        (__attribute__((address_space(3))) unsigned int*)l, 16, 0, 0);
}

// ---------------------------------------------------------------------------
// Kernel 1: transpose + convert weights to bf16, fold scales, stash biases.
// ---------------------------------------------------------------------------
__global__ void prep_weights(const float* __restrict__ Wq, const float* __restrict__ bq,
                             const float* __restrict__ Wk, const float* __restrict__ bk,
                             const float* __restrict__ Wv, const float* __restrict__ bv,
                             __hip_bfloat16* __restrict__ Wqt, __hip_bfloat16* __restrict__ Wkt,
                             __hip_bfloat16* __restrict__ Wvt, float* __restrict__ bias) {
    int i = blockIdx.x * 256 + threadIdx.x;  // 64 blocks * 256 = 16384 exactly
    int k = i >> 7, o = i & 127;
    Wqt[o * 128 + k] = __float2bfloat16(Wq[i] * QS);
    Wkt[o * 128 + k] = __float2bfloat16(Wk[i]);
    Wvt[o * 128 + k] = __float2bfloat16(Wv[i] * 0.25f);  // head-mean folded into V
    if (i < 128) {
        bias[i]       = bq[i] * QS;
        bias[128 + i] = bk[i];
        bias[256 + i] = bv[i] * 0.25f;
    }
}

// ---------------------------------------------------------------------------
// Kernel 2: Q/K/V projections via 16x16x32 bf16 MFMA.
//   Qo, Ko: row-major [B*N][128] bf16 (Q pre-scaled by C2/sqrt(128))
//   Vt:     transposed [B][128][N] bf16 (pre-scaled by 0.25)
// ---------------------------------------------------------------------------
__global__ __launch_bounds__(256) void proj_qkv(
        const float* __restrict__ x, const float* __restrict__ cond,
        const __hip_bfloat16* __restrict__ Wqt, const __hip_bfloat16* __restrict__ Wkt,
        const __hip_bfloat16* __restrict__ Wvt, const float* __restrict__ bias,
        __hip_bfloat16* __restrict__ Qo, __hip_bfloat16* __restrict__ Ko,
        __hip_bfloat16* __restrict__ Vt) {
    const int lane = threadIdx.x & 63, wv = threadIdx.x >> 6;
    const int l15 = lane & 15, g = lane >> 4;
    const int row0 = blockIdx.x * 64 + wv * 16;   // 256 blocks x 64 rows

    f32x4 qa[8], ka[8], va[8];
#pragma unroll
    for (int ot = 0; ot < 8; ++ot) {
        float b0 = bias[16 * ot + l15];
        float b1 = bias[128 + 16 * ot + l15];
        float b2 = bias[256 + 16 * ot + l15];
        qa[ot] = (f32x4){b0, b0, b0, b0};
        ka[ot] = (f32x4){b1, b1, b1, b1};
        va[ot] = (f32x4){b2, b2, b2, b2};
    }

    const float* xp = x    + (size_t)(row0 + l15) * 128 + 8 * g;
    const float* cp = cond + (size_t)(row0 + l15) * 128 + 8 * g;
#pragma unroll
    for (int kk = 0; kk < 4; ++kk) {
        float4 x0 = *(const float4*)(xp + 32 * kk);
        float4 x1 = *(const float4*)(xp + 32 * kk + 4);
        float4 c0 = *(const float4*)(cp + 32 * kk);
        float4 c1 = *(const float4*)(cp + 32 * kk + 4);
        bf16x8 xa = pack8(x0, x1);
        bf16x8 ca = pack8(c0, c1);
#pragma unroll
        for (int ot = 0; ot < 8; ++ot) {
            const int wo = (16 * ot + l15) * 128 + 32 * kk + 8 * g;
            qa[ot] = MFMA16(xa, *(const bf16x8*)(Wqt + wo), qa[ot]);
            ka[ot] = MFMA16(ca, *(const bf16x8*)(Wkt + wo), ka[ot]);
            va[ot] = MFMA16(ca, *(const bf16x8*)(Wvt + wo), va[ot]);
        }
    }

    // Q, K row-major stores (C/D layout: row = 4g+r, col = 16ot+l15)
#pragma unroll
    for (int ot = 0; ot < 8; ++ot)
#pragma unroll
        for (int r = 0; r < 4; ++r) {
            size_t idx = (size_t)(row0 + 4 * g + r) * 128 + 16 * ot + l15;
            Qo[idx] = __float2bfloat16(qa[ot][r]);
            Ko[idx] = __float2bfloat16(ka[ot][r]);
        }
    // V transposed store: lane holds 4 consecutive n for fixed d -> dwordx2
    const int bb = row0 >> 11, nn = (row0 & 2047) + 4 * g;
#pragma unroll
    for (int ot = 0; ot < 8; ++ot) {
        uint2 pr;
        pr.x = cvtpk_bf16(va[ot][0], va[ot][1]);
        pr.y = cvtpk_bf16(va[ot][2], va[ot][3]);
        *(uint2*)((unsigned short*)Vt + ((size_t)bb * 128 + 16 * ot + l15) * 2048 + nn) = pr;
    }
}

// ---------------------------------------------------------------------------
// Kernel 3: fused tanh-attention, LDS-staged (R6).
// Grid 512 = 8b x 2 m-halves x 32 q-tiles. Block: 512 thr / 8 waves,
// 64 q-rows x 1024 m. Per 64-m chunk (16 chunks):
//   - K chunk [64][128] bf16 and V chunk [128][64] bf16 staged to LDS via
//     global_load_lds dwordx4 (linear dest, XOR-swizzled SOURCE; reads use
//     the same XOR -> bank-conflict-managed ds_read_b128, rule #21).
//   - wave (qw=w&3, mw=w>>2): QK for q-sub qw (16 rows) x m-sub mw (32):
//     8 MFMA + tanh; writes block-shared A tile [64q][72m-stride] bf16.
//   - mid barrier = lgkmcnt(0) ONLY (stage loads stay in flight).
//   - PV: wave (qw, dw=mw) computes 16q x 64d: 16 MFMA from A + V_lds.
//   - end barrier = vmcnt(0) (own stage done) + s_barrier (everyone's).
// Epilogue: per-wave-disjoint (q,d) tiles -> unsafeAtomicAdd (2 contenders).
// ---------------------------------------------------------------------------
__global__ __launch_bounds__(512) void attn_main(
        const __hip_bfloat16* __restrict__ Q, const __hip_bfloat16* __restrict__ K,
        const __hip_bfloat16* __restrict__ Vt, const float* __restrict__ mask,
        float* __restrict__ out) {
    __shared__ __align__(16) char Kl[2][16384];   // [64 m][256B] per buf
    __shared__ __align__(16) char Vl[2][16384];   // [128 d][128B] per buf
    __shared__ __align__(16) char Al[64 * 144];   // [64 q][72 bf16]

    const int lane = threadIdx.x & 63, w = threadIdx.x >> 6;
    const int l15 = lane & 15, g = lane >> 4;
    const int qw = w & 3, mw = w >> 2, dw = mw;
    const int qt = blockIdx.x & 31;
    const int mh = (blockIdx.x >> 5) & 1;
    const int b  = blockIdx.x >> 6;
    const int n0 = qt * 64;
    const int mh0 = mh * 1024;

    const __hip_bfloat16* Qb = Q + ((size_t)b * 2048 + n0 + qw * 16) * 128;
    const char* Kg = (const char*)(K + (size_t)b * 2048 * 128);
    const char* Vg = (const char*)(Vt + (size_t)b * 128 * 2048);
    const float* mrow = mask + ((size_t)b * 2048 + n0 + qw * 16 + l15) * 2048
                        + mh0 + mw * 32 + 4 * g;

    bf16x8 qf[4];
#pragma unroll
    for (int h = 0; h < 4; ++h)
        qf[h] = *(const bf16x8*)(Qb + l15 * 128 + 32 * h + 8 * g);

    f32x4 oacc[4];
#pragma unroll
    for (int dtl = 0; dtl < 4; ++dtl) oacc[dtl] = (f32x4){0.f, 0.f, 0.f, 0.f};
    const f32x4 zero = (f32x4){0.f, 0.f, 0.f, 0.f};

    // ---- staging: 2 K-instr + 2 V-instr per wave (1 KB each, linear LDS) --
    auto STAGE = [&](int m0g, int bi) {
#pragma unroll
        for (int i = 0; i < 2; ++i) {
            const int t = w * 2 + i;
            const int o = t * 1024 + lane * 16;
            const int kr = o >> 8, kc = o & 255;
            gload_lds16(Kg + (size_t)(m0g + kr) * 256 + (kc ^ ((kr & 7) << 4)),
                        &Kl[bi][t * 1024]);
            const int vr = o >> 7, vc = o & 127;
            gload_lds16(Vg + (size_t)vr * 4096 + (size_t)m0g * 2 + (vc ^ ((vr & 7) << 4)),
                        &Vl[bi][t * 1024]);
        }
    };

    // prologue: stage chunk 0, prefetch mask chunk 0
    STAGE(mh0, 0);
    f32x4 mkc0 = *(const f32x4*)(mrow);
    f32x4 mkc1 = *(const f32x4*)(mrow + 16);
    asm volatile("s_waitcnt vmcnt(0)" ::: "memory");
    __builtin_amdgcn_s_barrier();

#pragma unroll 2
    for (int c = 0; c < 16; ++c) {
        const int bi = c & 1;
        const int m0g = mh0 + c * 64;
        // issue next chunk's stage + mask prefetch (stay in flight all chunk)
        if (c < 15) STAGE(m0g + 64, bi ^ 1);
        f32x4 mkn0, mkn1;
        if (c < 15) {
            mkn0 = *(const f32x4*)(mrow + (c + 1) * 64);
            mkn1 = *(const f32x4*)(mrow + (c + 1) * 64 + 16);
        }

        // ---- QK + tanh + A-write (wave's 16q x 32m) ----
#pragma unroll
        for (int st = 0; st < 2; ++st) {
            const int mr = mw * 32 + st * 16 + l15;
            const char* kb = &Kl[bi][mr * 256];
            const int sw = (mr & 7) << 4;
            f32x4 s0 = MFMA16(*(const bf16x8*)(kb + ((g * 16) ^ sw)),       qf[0], zero);
            f32x4 s1 = MFMA16(*(const bf16x8*)(kb + ((64 + g * 16) ^ sw)),  qf[1], zero);
            f32x4 s2 = MFMA16(*(const bf16x8*)(kb + ((128 + g * 16) ^ sw)), qf[2], zero);
            f32x4 s3 = MFMA16(*(const bf16x8*)(kb + ((192 + g * 16) ^ sw)), qf[3], zero);
            const f32x4 mk = st ? mkc1 : mkc0;
            float acd[4];
#pragma unroll
            for (int r = 0; r < 4; ++r) {
                float m2 = mk[r] * C2;
                float e0 = __builtin_amdgcn_exp2f(m2 + s0[r]);
                float e1 = __builtin_amdgcn_exp2f(m2 + s1[r]);
                float e2 = __builtin_amdgcn_exp2f(m2 + s2[r]);
                float e3 = __builtin_amdgcn_exp2f(m2 + s3[r]);
                float rs = __builtin_amdgcn_rcpf(1.f + e0) + __builtin_amdgcn_rcpf(1.f + e1)
                         + __builtin_amdgcn_rcpf(1.f + e2) + __builtin_amdgcn_rcpf(1.f + e3);
                acd[r] = 4.f - 2.f * rs;   // sum_h tanh(...)
            }
            uint2 pk;
            pk.x = cvtpk_bf16(acd[0], acd[1]);
            pk.y = cvtpk_bf16(acd[2], acd[3]);
            *(uint2*)(Al + (qw * 16 + l15) * 144 + (mw * 32 + st * 16 + 4 * g) * 2) = pk;
        }

        // A visible block-wide; do NOT drain vmcnt (stage stays in flight)
        asm volatile("s_waitcnt lgkmcnt(0)" ::: "memory");
        __builtin_amdgcn_s_barrier();

        // ---- PV: wave's 16q x 64d over this chunk's 64 m ----
#pragma unroll
        for (int ks = 0; ks < 2; ++ks) {
            bf16x8 af = *(const bf16x8*)(Al + (qw * 16 + l15) * 144 + (ks * 32 + 8 * g) * 2);
#pragma unroll
            for (int dtl = 0; dtl < 4; ++dtl) {
                const int dr = dw * 64 + dtl * 16 + l15;
                bf16x8 vf = *(const bf16x8*)(
                    &Vl[bi][dr * 128 + ((ks * 64 + g * 16) ^ ((dr & 7) << 4))]);
                oacc[dtl] = MFMA16(af, vf, oacc[dtl]);
            }
        }

        // own stage complete, then joint barrier: everyone staged + A/V reads done
        asm volatile("s_waitcnt vmcnt(0)" ::: "memory");
        __builtin_amdgcn_s_barrier();

        mkc0 = mkn0;
        mkc1 = mkn1;
    }

    // epilogue: per-wave-disjoint 16q x 64d tile; 2 m-half blocks contend
    float* ob = out + ((size_t)b * 2048 + n0 + qw * 16) * 128 + dw * 64;
#pragma unroll
    for (int dtl = 0; dtl < 4; ++dtl)
#pragma unroll
        for (int r = 0; r < 4; ++r)
            unsafeAtomicAdd(&ob[(size_t)(4 * g + r) * 128 + dtl * 16 + l15], oacc[dtl][r]);
}

// ---------------------------------------------------------------------------
extern "C" void kernel_launch(void* const* d_in, const int* in_sizes, int n_in,
                              void* d_out, int out_size, void* d_ws, size_t ws_size,
                              hipStream_t stream) {
    const float* x    = (const float*)d_in[0];
    const float* cond = (const float*)d_in[1];
    // d_in[2] = flags (unused by reference)
    const float* mask = (const float*)d_in[3];
    const float* Wq = (const float*)d_in[4];
    const float* bq = (const float*)d_in[5];
    const float* Wk = (const float*)d_in[6];
    const float* bk = (const float*)d_in[7];
    const float* Wv = (const float*)d_in[8];
    const float* bv = (const float*)d_in[9];
    float* out = (float*)d_out;

    char* ws = (char*)d_ws;
    __hip_bfloat16* Qo  = (__hip_bfloat16*)(ws);                       // 4 MB
    __hip_bfloat16* Ko  = (__hip_bfloat16*)(ws + (4  << 20));          // 4 MB
    __hip_bfloat16* Vt  = (__hip_bfloat16*)(ws + (8  << 20));          // 4 MB
    __hip_bfloat16* Wqt = (__hip_bfloat16*)(ws + (12 << 20));          // 32 KB
    __hip_bfloat16* Wkt = (__hip_bfloat16*)(ws + (12 << 20) + 32768);
    __hip_bfloat16* Wvt = (__hip_bfloat16*)(ws + (12 << 20) + 65536);
    float*          bias = (float*)(ws + (12 << 20) + 98304);          // 1.5 KB

    // out accumulates atomic partials from 2 m-half blocks -> zero it first
    hipMemsetAsync(d_out, 0, (size_t)out_size * sizeof(float), stream);

    prep_weights<<<64, 256, 0, stream>>>(Wq, bq, Wk, bk, Wv, bv, Wqt, Wkt, Wvt, bias);
    proj_qkv<<<256, 256, 0, stream>>>(x, cond, Wqt, Wkt, Wvt, bias, Qo, Ko, Vt);
    attn_main<<<512, 512, 0, stream>>>(Qo, Ko, Vt, mask, out);
}